// Round 8
// baseline (673.581 us; speedup 1.0000x reference)
//
#include <hip/hip_runtime.h>
#include <stdint.h>

#define N_IMGS 8
#define NLVL 5
#define TOT 392832          // total anchors across levels
#define PRE_K 1000
#define POST_K 1000
#define KSEL 5000           // 5 levels * 1000
#define MASKW 79            // ceil(5000/64)
#define MROWS 5056          // KSEL padded to 79 full 64-row chunks
#define NCHUNK 79

typedef unsigned long long u64;

struct Ptrs {
    const float* obj[5];
    const float* del[5];
    const float* anch;
};

__device__ __forceinline__ unsigned flipf(float f) {
    unsigned u = __float_as_uint(f);
    return (u & 0x80000000u) ? ~u : (u | 0x80000000u);
}

__device__ __forceinline__ void lvl_info(int t, int& l, int& off, int& W, int& H) {
    if (t < 294912)      { l = 0; off = 0;      W = 384; H = 256; }
    else if (t < 368640) { l = 1; off = 294912; W = 192; H = 128; }
    else if (t < 387072) { l = 2; off = 368640; W = 96;  H = 64;  }
    else if (t < 391680) { l = 3; off = 387072; W = 48;  H = 32;  }
    else                 { l = 4; off = 391680; W = 24;  H = 16;  }
}

// Decode one proposal exactly as the reference (f32, no FMA contraction).
__device__ void decode_one(const Ptrs& P, int n, int t, float bx[4], bool& valid, int& lvl) {
#pragma clang fp contract(off)
    int l, off, W, H;
    lvl_info(t, l, off, W, H);
    lvl = l;
    int i = t - off;
    int a = i % 3;
    int p = i / 3;
    int y = p / W, x = p - y * W;
    const float* D = P.del[l];
    size_t plane = (size_t)W * H;
    size_t base = ((size_t)n * 12 + (size_t)a * 4) * plane + (size_t)y * W + x;
    float dx = D[base];
    float dy = D[base + plane];
    float dw = D[base + 2 * plane];
    float dh = D[base + 3 * plane];
    const float* an = P.anch + (size_t)t * 4;
    float a0 = an[0], a1 = an[1], a2 = an[2], a3 = an[3];
    float wa = a2 - a0, ha = a3 - a1;
    float cxa = a0 + 0.5f * wa, cya = a1 + 0.5f * ha;
    const float CLIP = 4.135166556742356f;  // log(1000/16) rounded to f32
    dw = fminf(dw, CLIP);
    dh = fminf(dh, CLIP);
    float cx = dx * wa + cxa;
    float cy = dy * ha + cya;
    float pw = expf(dw) * wa;
    float ph = expf(dh) * ha;
    float x1 = cx - 0.5f * pw, y1 = cy - 0.5f * ph;
    float x2 = cx + 0.5f * pw, y2 = cy + 0.5f * ph;
    x1 = fminf(fmaxf(x1, 0.f), 1536.f);
    x2 = fminf(fmaxf(x2, 0.f), 1536.f);
    y1 = fminf(fmaxf(y1, 0.f), 1024.f);
    y2 = fminf(fmaxf(y2, 0.f), 1024.f);
    bx[0] = x1; bx[1] = y1; bx[2] = x2; bx[3] = y2;
    valid = ((x2 - x1) >= 1e-3f) && ((y2 - y1) >= 1e-3f);
}

__global__ void k_init(int* vcnt) {
    int i = threadIdx.x;
    if (i < N_IMGS) vcnt[i] = KSEL;
}

__global__ void k_zero_out(float* out, int n) {
    int i = blockIdx.x * blockDim.x + threadIdx.x;
    if (i < n) out[i] = 0.f;
}

// Flatten objectness into (h,w,a) order per level, store order-flipped bits.
__global__ void k_scores(Ptrs P, unsigned* scores) {
    int idx = blockIdx.x * blockDim.x + threadIdx.x;
    if (idx >= N_IMGS * TOT) return;
    int n = idx / TOT, t = idx - n * TOT;
    int l, off, W, H;
    lvl_info(t, l, off, W, H);
    int i = t - off;
    int a = i % 3;
    int p = i / 3;
    int y = p / W, x = p - y * W;
    const float* O = P.obj[l];
    float v = O[(((size_t)n * 3 + a) * H + y) * (size_t)W + x];
    scores[idx] = flipf(v);
}

// Exact top-1000 per (image, level), lax.top_k tie semantics (score desc, index asc).
#define HCOPY 4100          // 4096 bins + 4 pad (bank decorrelation between copies)
#define CANDMAX 4096
__global__ __launch_bounds__(1024) void k_select(const unsigned* scores, uint2* sel) {
    int task = blockIdx.x;
    int n = task / 5, l = task % 5;
    int off, len;
    switch (l) {
        case 0: off = 0;      len = 294912; break;
        case 1: off = 294912; len = 73728;  break;
        case 2: off = 368640; len = 18432;  break;
        case 3: off = 387072; len = 4608;   break;
        default: off = 391680; len = 1152;  break;
    }
    const unsigned* S = scores + (size_t)n * TOT + off;
    const uint4* S4 = (const uint4*)S;
    int len4 = len >> 2;
    int t = threadIdx.x;

    __shared__ __align__(16) char smem[2 * HCOPY * 4];   // hist, later reused as cand
    unsigned* hist = (unsigned*)smem;
    unsigned long long* cand = (unsigned long long*)smem;
    __shared__ unsigned suf[1024];
    __shared__ unsigned sh_pivot, sh_krem;
    __shared__ int sh_ngt, sh_nc;

    // zero both hist copies
    for (int i = t; i < 2 * HCOPY; i += 1024) hist[i] = 0u;
    __syncthreads();

    // 12-bit histogram, copy = t&1
    unsigned* myh = hist + (t & 1) * HCOPY;
    for (int i = t; i < len4; i += 1024) {
        uint4 v = S4[i];
        atomicAdd(&myh[v.x >> 20], 1u);
        atomicAdd(&myh[v.y >> 20], 1u);
        atomicAdd(&myh[v.z >> 20], 1u);
        atomicAdd(&myh[v.w >> 20], 1u);
    }
    __syncthreads();
    // reduce copies
    for (int i = t; i < 4096; i += 1024) hist[i] += hist[HCOPY + i];
    __syncthreads();
    // per-group sums (4 bins/thread), inclusive suffix scan
    suf[t] = hist[4 * t] + hist[4 * t + 1] + hist[4 * t + 2] + hist[4 * t + 3];
    for (int d = 1; d < 1024; d <<= 1) {
        __syncthreads();
        unsigned v = (t + d < 1024) ? suf[t + d] : 0u;
        __syncthreads();
        suf[t] += v;
    }
    __syncthreads();
    // boundary group: suf[t] >= K, suf[t+1] < K
    unsigned above = (t == 1023) ? 0u : suf[t + 1];
    if (suf[t] >= PRE_K && above < PRE_K) {
        int b = 4 * t + 3;
        unsigned c = above;
        while (c + hist[b] < PRE_K) { c += hist[b]; --b; }
        sh_pivot = (unsigned)b;
        sh_krem = PRE_K - c;          // how many to take from pivot bin
        sh_ngt = 0; sh_nc = 0;
    }
    __syncthreads();
    unsigned pivot = sh_pivot;
    int krem = (int)sh_krem;
    __syncthreads();   // hist no longer needed; smem becomes cand

    // compact pass
    uint2* out = sel + (size_t)task * PRE_K;
    for (int i = t; i < len4; i += 1024) {
        uint4 v4 = S4[i];
        unsigned vv[4] = {v4.x, v4.y, v4.z, v4.w};
#pragma unroll
        for (int q = 0; q < 4; ++q) {
            unsigned v = vv[q];
            unsigned b = v >> 20;
            if (b > pivot) {
                int slot = atomicAdd(&sh_ngt, 1);
                out[slot] = make_uint2(v, (unsigned)(off + 4 * i + q));
            } else if (b == pivot) {
                int c = atomicAdd(&sh_nc, 1);
                if (c < CANDMAX)
                    cand[c] = ((unsigned long long)v << 32) | (unsigned)(off + 4 * i + q);
            }
        }
    }
    __syncthreads();
    int C = min(sh_nc, CANDMAX);
    int nbase = sh_ngt;               // == PRE_K - krem
    // exact rank among pivot-bin candidates (uniform j-loop -> LDS broadcast reads)
    for (int i = t; i < C; i += 1024) {
        unsigned long long a = cand[i];
        unsigned vi = (unsigned)(a >> 32), xi = (unsigned)a;
        int rank = 0;
        for (int j = 0; j < C; ++j) {
            unsigned long long bj = cand[j];
            unsigned vj = (unsigned)(bj >> 32), xj = (unsigned)bj;
            rank += (vj > vi) || (vj == vi && xj < xi);
        }
        if (rank < krem) out[nbase + rank] = make_uint2(vi, xi);
    }
}

// Build sort keys: ascending key order == (score desc, concat position asc).
// Invalid (too-small after clip) entries forced to the tail.
__global__ void k_keys(Ptrs P, const uint2* sel, unsigned long long* keys) {
    int idx = blockIdx.x * blockDim.x + threadIdx.x;
    if (idx >= N_IMGS * KSEL) return;
    int n = idx / KSEL;
    uint2 s = sel[idx];
    float bx[4]; bool valid; int l;
    decode_one(P, n, (int)s.y, bx, valid, l);
    unsigned long long key;
    if (valid) key = ((unsigned long long)(~s.x) << 32) | (unsigned long long)s.y;
    else       key = 0xFFFFFFFF00000000ull | (unsigned long long)s.y;
    keys[idx] = key;
}

// Bitonic sort of 5000 keys (padded to 8192) per image, in 64 KiB LDS.
__global__ __launch_bounds__(1024) void k_sort(unsigned long long* keys) {
    extern __shared__ unsigned long long s[];
    int n = blockIdx.x;
    unsigned long long* K = keys + (size_t)n * KSEL;
    for (int i = threadIdx.x; i < 8192; i += 1024)
        s[i] = (i < KSEL) ? K[i] : ~0ull;
    for (int k = 2; k <= 8192; k <<= 1) {
        for (int j = k >> 1; j > 0; j >>= 1) {
            __syncthreads();
            for (int i = threadIdx.x; i < 8192; i += 1024) {
                int l = i ^ j;
                if (l > i) {
                    unsigned long long a = s[i], b = s[l];
                    bool asc = ((i & k) == 0);
                    if (asc ? (a > b) : (a < b)) { s[i] = b; s[l] = a; }
                }
            }
        }
    }
    __syncthreads();
    for (int i = threadIdx.x; i < KSEL; i += 1024) K[i] = s[i];
}

// Re-decode in sorted order; emit clipped boxes + level-offset NMS boxes; find valid count.
__global__ void k_decode(Ptrs P, const unsigned long long* keys,
                         float4* boxes, float4* nboxes, int* vcnt) {
    int idx = blockIdx.x * blockDim.x + threadIdx.x;
    if (idx >= N_IMGS * KSEL) return;
    int n = idx / KSEL, r = idx - n * KSEL;
    unsigned long long key = keys[idx];
    if ((key >> 32) == 0xFFFFFFFFull) {
        boxes[idx] = make_float4(0.f, 0.f, 0.f, 0.f);
        nboxes[idx] = make_float4(0.f, 0.f, 0.f, 0.f);
        atomicMin(&vcnt[n], r);
        return;
    }
    int t = (int)(key & 0xFFFFFFFFull);
    float bx[4]; bool valid; int l;
    decode_one(P, n, t, bx, valid, l);
    boxes[idx] = make_float4(bx[0], bx[1], bx[2], bx[3]);
    float offv = (float)l * 1537.0f;   // (max(H,W)+1) * level
    nboxes[idx] = make_float4(bx[0] + offv, bx[1] + offv, bx[2] + offv, bx[3] + offv);
}

// Suppression bitmask, row-major: mask[(n*MROWS + r)*MASKW + cb], bit cc set iff
// IoU(r, cb*64+cc) > 0.7 and col > r. Only upper-triangular blocks (cb >= rb)
// written. Lower-tri words may be read by k_scan's row-wide OR but only fold into
// rem words already consumed — value is irrelevant by construction.
__global__ __launch_bounds__(64) void k_mask(const float4* nboxes, u64* mask) {
#pragma clang fp contract(off)
    int rb = blockIdx.x, cb = blockIdx.y, n = blockIdx.z;
    if (cb < rb) return;
    __shared__ float4 cbox[64];
    int tid = threadIdx.x;
    int c0 = cb * 64;
    cbox[tid] = (c0 + tid < KSEL) ? nboxes[(size_t)n * KSEL + c0 + tid]
                                  : make_float4(0.f, 0.f, 0.f, 0.f);
    __syncthreads();
    int r = rb * 64 + tid;
    if (r >= KSEL) return;
    float4 rb4 = nboxes[(size_t)n * KSEL + r];
    float areaR = (rb4.z - rb4.x) * (rb4.w - rb4.y);
    u64 bits = 0ull;
    for (int cc = 0; cc < 64; ++cc) {
        int c = c0 + cc;
        if (c >= KSEL) break;
        if (c <= r) continue;
        float4 c4 = cbox[cc];
        float areaC = (c4.z - c4.x) * (c4.w - c4.y);
        float ltx = fmaxf(rb4.x, c4.x), lty = fmaxf(rb4.y, c4.y);
        float rbx = fminf(rb4.z, c4.z), rby = fminf(rb4.w, c4.w);
        float wv = fmaxf(rbx - ltx, 0.f), hv = fmaxf(rby - lty, 0.f);
        float inter = wv * hv;
        float iou = inter / (areaR + areaC - inter);   // NaN compares false, as in JAX
        if (iou > 0.7f) bits |= (1ull << cc);
    }
    mask[((size_t)n * MROWS + r) * MASKW + cb] = bits;
}

__device__ __forceinline__ u64 bcast64(u64 v, int src) {
    unsigned lo = (unsigned)__builtin_amdgcn_readlane((int)(unsigned)v, src);
    unsigned hi = (unsigned)__builtin_amdgcn_readlane((int)(unsigned)(v >> 32), src);
    return ((u64)hi << 32) | (u64)lo;
}

// Single-wave greedy NMS scan. rem distributed in registers (lane L owns word L,
// and word 64+L for L<15). Per chunk: 1 readlane for cur; ctz-jump chain; then
// the newly kept rows' mask rows are staged via global_load_lds (NO result
// VGPRs -> all issue back-to-back, one vmcnt(0) round trip per batch of 16),
// ORed into rem from LDS (conflict-free ds_read_b64). Diagonal word of the
// next chunk prefetched before the batch wait so the two latencies overlap.
#define BATCH 16
__global__ __launch_bounds__(64) void k_scan(const u64* mask, const int* vcnt,
                                             int* keep, int* nkept) {
    __shared__ __align__(16) u64 lbuf[BATCH * 80];  // 16 rows x (79 words + overrun pad)
    int n = blockIdx.x, lane = threadIdx.x;
    int V = vcnt[n];
    const u64* M = mask + (size_t)n * MROWS * MASKW;

    u64 rem_lo = 0ull, rem_hi = 0ull;
    int cnt = 0;
    bool full = false;
    int nchunks = (V + 63) >> 6;

    u64 wc_next = M[(size_t)lane * MASKW];   // word 0 of rows 0..63
    for (int c = 0; c < nchunks && !full; ++c) {
        u64 wc = wc_next;
        u64 cur = bcast64((c < 64) ? rem_lo : rem_hi, c & 63);

        int base = c * 64;
        int jmax = V - base; if (jmax > 64) jmax = 64;
        u64 avail = ~cur;
        if (jmax < 64) avail &= (1ull << jmax) - 1ull;
        u64 keptbits = 0ull;
        while (avail) {
            int j = __builtin_ctzll(avail);
            if (lane == 0) keep[n * POST_K + cnt] = base + j;
            ++cnt;
            keptbits |= 1ull << j;
            if (cnt == POST_K) { full = true; break; }
            u64 wcj = bcast64(wc, j);
            avail &= avail - 1;        // clear bit j
            avail &= ~wcj;             // suppress within-chunk victims
        }

        // prefetch next chunk's diagonal word; latency shared with batch wait
        if (c + 1 < nchunks)
            wc_next = M[((size_t)(c + 1) * 64 + lane) * MASKW + (c + 1)];

        if (full) break;

        u64 kb = keptbits;
        while (kb) {
            int nb = 0;
#pragma unroll
            for (int q = 0; q < BATCH; ++q) {
                if (kb) {
                    int j = (int)__builtin_ctzll(kb);
                    kb &= kb - 1;
                    ++nb;
                    if (lane < 40) {   // 40 lanes x 16B = 640B >= 632B row
                        const char* src = (const char*)(M + (size_t)(base + j) * MASKW);
                        __builtin_amdgcn_global_load_lds(
                            (const __attribute__((address_space(1))) unsigned int*)(src + (size_t)lane * 16),
                            (__attribute__((address_space(3))) unsigned int*)((char*)lbuf + q * 640),
                            16, 0, 0);
                    }
                }
            }
            asm volatile("s_waitcnt vmcnt(0)" ::: "memory");
            for (int q = 0; q < nb; ++q) {
                rem_lo |= lbuf[q * 80 + lane];
                if (lane < 15) rem_hi |= lbuf[q * 80 + 64 + lane];
            }
        }
    }
    if (lane == 0) nkept[n] = cnt;
}

__global__ void k_out(const float4* boxes, const int* keep, const int* nkept, float4* out) {
    int idx = blockIdx.x * blockDim.x + threadIdx.x;
    if (idx >= N_IMGS * POST_K) return;
    int n = idx / POST_K, k = idx - n * POST_K;
    float4 v = make_float4(0.f, 0.f, 0.f, 0.f);
    if (k < nkept[n]) v = boxes[(size_t)n * KSEL + keep[n * POST_K + k]];
    out[idx] = v;
}

extern "C" void kernel_launch(void* const* d_in, const int* in_sizes, int n_in,
                              void* d_out, int out_size, void* d_ws, size_t ws_size,
                              hipStream_t stream) {
    // dict order: obj0, delta0, obj1, delta1, ..., obj4, delta4, anchors
    Ptrs P;
    for (int l = 0; l < 5; ++l) {
        P.obj[l] = (const float*)d_in[2 * l];
        P.del[l] = (const float*)d_in[2 * l + 1];
    }
    P.anch = (const float*)d_in[10];

    // workspace carve
    size_t o = 0;
    auto alloc = [&](size_t bytes) {
        size_t cur = o;
        o = (o + bytes + 255) & ~(size_t)255;
        return cur;
    };
    size_t off_scores = alloc((size_t)N_IMGS * TOT * 4);
    size_t off_sel    = alloc((size_t)N_IMGS * KSEL * 8);
    size_t off_keys   = alloc((size_t)N_IMGS * KSEL * 8);
    size_t off_boxes  = alloc((size_t)N_IMGS * KSEL * 16);
    size_t off_nbox   = alloc((size_t)N_IMGS * KSEL * 16);
    size_t off_mask   = alloc((size_t)N_IMGS * MROWS * MASKW * 8);
    size_t off_vcnt   = alloc(N_IMGS * 4);
    size_t off_keep   = alloc((size_t)N_IMGS * POST_K * 4);
    size_t off_nkept  = alloc(N_IMGS * 4);

    float* out = (float*)d_out;
    if (o > ws_size) {  // workspace too small: emit zeros (visible failure, no crash)
        k_zero_out<<<(out_size + 255) / 256, 256, 0, stream>>>(out, out_size);
        return;
    }

    char* w = (char*)d_ws;
    unsigned* scores          = (unsigned*)(w + off_scores);
    uint2* sel                = (uint2*)(w + off_sel);
    unsigned long long* keys  = (unsigned long long*)(w + off_keys);
    float4* boxes             = (float4*)(w + off_boxes);
    float4* nboxes            = (float4*)(w + off_nbox);
    u64* mask                 = (u64*)(w + off_mask);
    int* vcnt                 = (int*)(w + off_vcnt);
    int* keep                 = (int*)(w + off_keep);
    int* nkept                = (int*)(w + off_nkept);

    k_init<<<1, 32, 0, stream>>>(vcnt);
    k_scores<<<(N_IMGS * TOT + 255) / 256, 256, 0, stream>>>(P, scores);
    k_select<<<N_IMGS * NLVL, 1024, 0, stream>>>(scores, sel);
    k_keys<<<(N_IMGS * KSEL + 255) / 256, 256, 0, stream>>>(P, sel, keys);
    k_sort<<<N_IMGS, 1024, 65536, stream>>>(keys);
    k_decode<<<(N_IMGS * KSEL + 255) / 256, 256, 0, stream>>>(P, keys, boxes, nboxes, vcnt);
    k_mask<<<dim3(NCHUNK, MASKW, N_IMGS), 64, 0, stream>>>(nboxes, mask);
    k_scan<<<N_IMGS, 64, 0, stream>>>(mask, vcnt, keep, nkept);
    k_out<<<(N_IMGS * POST_K + 255) / 256, 256, 0, stream>>>((const float4*)boxes, keep, nkept, (float4*)d_out);
}

// Round 9
// 462.117 us; speedup vs baseline: 1.4576x; 1.4576x over previous
//
#include <hip/hip_runtime.h>
#include <stdint.h>

#define N_IMGS 8
#define NLVL 5
#define TOT 392832          // total anchors across levels
#define PRE_K 1000
#define POST_K 1000
#define KSEL 5000           // 5 levels * 1000
#define MASKW 79            // ceil(5000/64)
#define MROWS 5056          // KSEL padded to 79 full 64-row chunks
#define NCHUNK 79

typedef unsigned long long u64;

struct Ptrs {
    const float* obj[5];
    const float* del[5];
    const float* anch;
};

__device__ __forceinline__ unsigned flipf(float f) {
    unsigned u = __float_as_uint(f);
    return (u & 0x80000000u) ? ~u : (u | 0x80000000u);
}

__device__ __forceinline__ void lvl_info(int t, int& l, int& off, int& W, int& H) {
    if (t < 294912)      { l = 0; off = 0;      W = 384; H = 256; }
    else if (t < 368640) { l = 1; off = 294912; W = 192; H = 128; }
    else if (t < 387072) { l = 2; off = 368640; W = 96;  H = 64;  }
    else if (t < 391680) { l = 3; off = 387072; W = 48;  H = 32;  }
    else                 { l = 4; off = 391680; W = 24;  H = 16;  }
}

// Decode one proposal exactly as the reference (f32, no FMA contraction).
__device__ void decode_one(const Ptrs& P, int n, int t, float bx[4], bool& valid, int& lvl) {
#pragma clang fp contract(off)
    int l, off, W, H;
    lvl_info(t, l, off, W, H);
    lvl = l;
    int i = t - off;
    int a = i % 3;
    int p = i / 3;
    int y = p / W, x = p - y * W;
    const float* D = P.del[l];
    size_t plane = (size_t)W * H;
    size_t base = ((size_t)n * 12 + (size_t)a * 4) * plane + (size_t)y * W + x;
    float dx = D[base];
    float dy = D[base + plane];
    float dw = D[base + 2 * plane];
    float dh = D[base + 3 * plane];
    const float* an = P.anch + (size_t)t * 4;
    float a0 = an[0], a1 = an[1], a2 = an[2], a3 = an[3];
    float wa = a2 - a0, ha = a3 - a1;
    float cxa = a0 + 0.5f * wa, cya = a1 + 0.5f * ha;
    const float CLIP = 4.135166556742356f;  // log(1000/16) rounded to f32
    dw = fminf(dw, CLIP);
    dh = fminf(dh, CLIP);
    float cx = dx * wa + cxa;
    float cy = dy * ha + cya;
    float pw = expf(dw) * wa;
    float ph = expf(dh) * ha;
    float x1 = cx - 0.5f * pw, y1 = cy - 0.5f * ph;
    float x2 = cx + 0.5f * pw, y2 = cy + 0.5f * ph;
    x1 = fminf(fmaxf(x1, 0.f), 1536.f);
    x2 = fminf(fmaxf(x2, 0.f), 1536.f);
    y1 = fminf(fmaxf(y1, 0.f), 1024.f);
    y2 = fminf(fmaxf(y2, 0.f), 1024.f);
    bx[0] = x1; bx[1] = y1; bx[2] = x2; bx[3] = y2;
    valid = ((x2 - x1) >= 1e-3f) && ((y2 - y1) >= 1e-3f);
}

__global__ void k_init(int* vcnt) {
    int i = threadIdx.x;
    if (i < N_IMGS) vcnt[i] = KSEL;
}

__global__ void k_zero_out(float* out, int n) {
    int i = blockIdx.x * blockDim.x + threadIdx.x;
    if (i < n) out[i] = 0.f;
}

// Flatten objectness into (h,w,a) order per level, store order-flipped bits.
__global__ void k_scores(Ptrs P, unsigned* scores) {
    int idx = blockIdx.x * blockDim.x + threadIdx.x;
    if (idx >= N_IMGS * TOT) return;
    int n = idx / TOT, t = idx - n * TOT;
    int l, off, W, H;
    lvl_info(t, l, off, W, H);
    int i = t - off;
    int a = i % 3;
    int p = i / 3;
    int y = p / W, x = p - y * W;
    const float* O = P.obj[l];
    float v = O[(((size_t)n * 3 + a) * H + y) * (size_t)W + x];
    scores[idx] = flipf(v);
}

// Exact top-1000 per (image, level), lax.top_k tie semantics (score desc, index asc).
#define HCOPY 4100          // 4096 bins + 4 pad (bank decorrelation between copies)
#define CANDMAX 4096
__global__ __launch_bounds__(1024) void k_select(const unsigned* scores, uint2* sel) {
    int task = blockIdx.x;
    int n = task / 5, l = task % 5;
    int off, len;
    switch (l) {
        case 0: off = 0;      len = 294912; break;
        case 1: off = 294912; len = 73728;  break;
        case 2: off = 368640; len = 18432;  break;
        case 3: off = 387072; len = 4608;   break;
        default: off = 391680; len = 1152;  break;
    }
    const unsigned* S = scores + (size_t)n * TOT + off;
    const uint4* S4 = (const uint4*)S;
    int len4 = len >> 2;
    int t = threadIdx.x;

    __shared__ __align__(16) char smem[2 * HCOPY * 4];   // hist, later reused as cand
    unsigned* hist = (unsigned*)smem;
    unsigned long long* cand = (unsigned long long*)smem;
    __shared__ unsigned suf[1024];
    __shared__ unsigned sh_pivot, sh_krem;
    __shared__ int sh_ngt, sh_nc;

    // zero both hist copies
    for (int i = t; i < 2 * HCOPY; i += 1024) hist[i] = 0u;
    __syncthreads();

    // 12-bit histogram, copy = t&1
    unsigned* myh = hist + (t & 1) * HCOPY;
    for (int i = t; i < len4; i += 1024) {
        uint4 v = S4[i];
        atomicAdd(&myh[v.x >> 20], 1u);
        atomicAdd(&myh[v.y >> 20], 1u);
        atomicAdd(&myh[v.z >> 20], 1u);
        atomicAdd(&myh[v.w >> 20], 1u);
    }
    __syncthreads();
    // reduce copies
    for (int i = t; i < 4096; i += 1024) hist[i] += hist[HCOPY + i];
    __syncthreads();
    // per-group sums (4 bins/thread), inclusive suffix scan
    suf[t] = hist[4 * t] + hist[4 * t + 1] + hist[4 * t + 2] + hist[4 * t + 3];
    for (int d = 1; d < 1024; d <<= 1) {
        __syncthreads();
        unsigned v = (t + d < 1024) ? suf[t + d] : 0u;
        __syncthreads();
        suf[t] += v;
    }
    __syncthreads();
    // boundary group: suf[t] >= K, suf[t+1] < K
    unsigned above = (t == 1023) ? 0u : suf[t + 1];
    if (suf[t] >= PRE_K && above < PRE_K) {
        int b = 4 * t + 3;
        unsigned c = above;
        while (c + hist[b] < PRE_K) { c += hist[b]; --b; }
        sh_pivot = (unsigned)b;
        sh_krem = PRE_K - c;          // how many to take from pivot bin
        sh_ngt = 0; sh_nc = 0;
    }
    __syncthreads();
    unsigned pivot = sh_pivot;
    int krem = (int)sh_krem;
    __syncthreads();   // hist no longer needed; smem becomes cand

    // compact pass
    uint2* out = sel + (size_t)task * PRE_K;
    for (int i = t; i < len4; i += 1024) {
        uint4 v4 = S4[i];
        unsigned vv[4] = {v4.x, v4.y, v4.z, v4.w};
#pragma unroll
        for (int q = 0; q < 4; ++q) {
            unsigned v = vv[q];
            unsigned b = v >> 20;
            if (b > pivot) {
                int slot = atomicAdd(&sh_ngt, 1);
                out[slot] = make_uint2(v, (unsigned)(off + 4 * i + q));
            } else if (b == pivot) {
                int c = atomicAdd(&sh_nc, 1);
                if (c < CANDMAX)
                    cand[c] = ((unsigned long long)v << 32) | (unsigned)(off + 4 * i + q);
            }
        }
    }
    __syncthreads();
    int C = min(sh_nc, CANDMAX);
    int nbase = sh_ngt;               // == PRE_K - krem
    // exact rank among pivot-bin candidates (uniform j-loop -> LDS broadcast reads)
    for (int i = t; i < C; i += 1024) {
        unsigned long long a = cand[i];
        unsigned vi = (unsigned)(a >> 32), xi = (unsigned)a;
        int rank = 0;
        for (int j = 0; j < C; ++j) {
            unsigned long long bj = cand[j];
            unsigned vj = (unsigned)(bj >> 32), xj = (unsigned)bj;
            rank += (vj > vi) || (vj == vi && xj < xi);
        }
        if (rank < krem) out[nbase + rank] = make_uint2(vi, xi);
    }
}

// Build sort keys: ascending key order == (score desc, concat position asc).
// Invalid (too-small after clip) entries forced to the tail.
__global__ void k_keys(Ptrs P, const uint2* sel, unsigned long long* keys) {
    int idx = blockIdx.x * blockDim.x + threadIdx.x;
    if (idx >= N_IMGS * KSEL) return;
    int n = idx / KSEL;
    uint2 s = sel[idx];
    float bx[4]; bool valid; int l;
    decode_one(P, n, (int)s.y, bx, valid, l);
    unsigned long long key;
    if (valid) key = ((unsigned long long)(~s.x) << 32) | (unsigned long long)s.y;
    else       key = 0xFFFFFFFF00000000ull | (unsigned long long)s.y;
    keys[idx] = key;
}

// Bitonic sort of 5000 keys (padded to 8192) per image, in 64 KiB LDS.
__global__ __launch_bounds__(1024) void k_sort(unsigned long long* keys) {
    extern __shared__ unsigned long long s[];
    int n = blockIdx.x;
    unsigned long long* K = keys + (size_t)n * KSEL;
    for (int i = threadIdx.x; i < 8192; i += 1024)
        s[i] = (i < KSEL) ? K[i] : ~0ull;
    for (int k = 2; k <= 8192; k <<= 1) {
        for (int j = k >> 1; j > 0; j >>= 1) {
            __syncthreads();
            for (int i = threadIdx.x; i < 8192; i += 1024) {
                int l = i ^ j;
                if (l > i) {
                    unsigned long long a = s[i], b = s[l];
                    bool asc = ((i & k) == 0);
                    if (asc ? (a > b) : (a < b)) { s[i] = b; s[l] = a; }
                }
            }
        }
    }
    __syncthreads();
    for (int i = threadIdx.x; i < KSEL; i += 1024) K[i] = s[i];
}

// Re-decode in sorted order; emit clipped boxes + level-offset NMS boxes; find valid count.
__global__ void k_decode(Ptrs P, const unsigned long long* keys,
                         float4* boxes, float4* nboxes, int* vcnt) {
    int idx = blockIdx.x * blockDim.x + threadIdx.x;
    if (idx >= N_IMGS * KSEL) return;
    int n = idx / KSEL, r = idx - n * KSEL;
    unsigned long long key = keys[idx];
    if ((key >> 32) == 0xFFFFFFFFull) {
        boxes[idx] = make_float4(0.f, 0.f, 0.f, 0.f);
        nboxes[idx] = make_float4(0.f, 0.f, 0.f, 0.f);
        atomicMin(&vcnt[n], r);
        return;
    }
    int t = (int)(key & 0xFFFFFFFFull);
    float bx[4]; bool valid; int l;
    decode_one(P, n, t, bx, valid, l);
    boxes[idx] = make_float4(bx[0], bx[1], bx[2], bx[3]);
    float offv = (float)l * 1537.0f;   // (max(H,W)+1) * level
    nboxes[idx] = make_float4(bx[0] + offv, bx[1] + offv, bx[2] + offv, bx[3] + offv);
}

// Suppression bitmask, TRANSPOSED layout: maskT[(n*MASKW + cword)*MROWS + r].
// Bit cc of maskT[cword][r] set iff IoU(r, cword*64+cc) > 0.7 and col > r.
// Only upper-triangular blocks (cb >= rb) written; k_scan only reads
// maskT[cword][r] for rows r kept in chunks <= cword, which are all written.
__global__ __launch_bounds__(64) void k_mask(const float4* nboxes, u64* maskT) {
#pragma clang fp contract(off)
    int rb = blockIdx.x, cb = blockIdx.y, n = blockIdx.z;
    if (cb < rb) return;
    __shared__ float4 cbox[64];
    int tid = threadIdx.x;
    int c0 = cb * 64;
    cbox[tid] = (c0 + tid < KSEL) ? nboxes[(size_t)n * KSEL + c0 + tid]
                                  : make_float4(0.f, 0.f, 0.f, 0.f);
    __syncthreads();
    int r = rb * 64 + tid;
    if (r >= KSEL) return;
    float4 rb4 = nboxes[(size_t)n * KSEL + r];
    float areaR = (rb4.z - rb4.x) * (rb4.w - rb4.y);
    u64 bits = 0ull;
    for (int cc = 0; cc < 64; ++cc) {
        int c = c0 + cc;
        if (c >= KSEL) break;
        if (c <= r) continue;
        float4 c4 = cbox[cc];
        float areaC = (c4.z - c4.x) * (c4.w - c4.y);
        float ltx = fmaxf(rb4.x, c4.x), lty = fmaxf(rb4.y, c4.y);
        float rbx = fminf(rb4.z, c4.z), rby = fminf(rb4.w, c4.w);
        float wv = fmaxf(rbx - ltx, 0.f), hv = fmaxf(rby - lty, 0.f);
        float inter = wv * hv;
        float iou = inter / (areaR + areaC - inter);   // NaN compares false, as in JAX
        if (iou > 0.7f) bits |= (1ull << cc);
    }
    maskT[((size_t)n * MASKW + cb) * MROWS + r] = bits;   // coalesced across tid
}

__device__ __forceinline__ u64 bcast64(u64 v, int src) {
    unsigned lo = (unsigned)__builtin_amdgcn_readlane((int)(unsigned)v, src);
    unsigned hi = (unsigned)__builtin_amdgcn_readlane((int)(unsigned)(v >> 32), src);
    return ((u64)hi << 32) | (u64)lo;
}

// Wave64 OR-reduce via DPP (AMD GCN canonical sequence), result in lane 63.
__device__ __forceinline__ unsigned or_red_dpp(unsigned v) {
    v |= (unsigned)__builtin_amdgcn_update_dpp(0, (int)v, 0x111, 0xf, 0xf, true);  // row_shr:1
    v |= (unsigned)__builtin_amdgcn_update_dpp(0, (int)v, 0x112, 0xf, 0xf, true);  // row_shr:2
    v |= (unsigned)__builtin_amdgcn_update_dpp(0, (int)v, 0x114, 0xf, 0xf, true);  // row_shr:4
    v |= (unsigned)__builtin_amdgcn_update_dpp(0, (int)v, 0x118, 0xf, 0xf, true);  // row_shr:8
    v |= (unsigned)__builtin_amdgcn_update_dpp(0, (int)v, 0x142, 0xa, 0xf, false); // row_bcast:15
    v |= (unsigned)__builtin_amdgcn_update_dpp(0, (int)v, 0x143, 0xc, 0xf, false); // row_bcast:31
    return v;
}

// Single-wave greedy NMS scan, fully software-pipelined: all loads for chunk c
// are issued during chunk c-1, so the per-chunk critical path is VALU/SALU only
// (DPP OR-reduce + ctz chain). Inputs per chunk c:
//   bulk[16]: word c of rows kept through chunk c-2 (unrolled register gather);
//   nc: word c of ALL rows of chunk c-1 (coalesced), masked by keptbits_{c-1};
//   wc: word c of chunk c's rows (diagonal, coalesced).
// Coverage: bulk (chunks <= c-2) + nc (chunk c-1) + in-chain wc (chunk c) = all.
// OR double-counting is harmless; keep_lds zero-init keeps idle gather slots on
// row 0 (valid, masked out by the cnt predicate).
__global__ __launch_bounds__(64, 1) void k_scan(const u64* maskT, const int* vcnt,
                                                int* keep, int* nkept) {
    __shared__ int keep_lds[1024];
    int n = blockIdx.x, lane = threadIdx.x;
    int V = vcnt[n];
    const u64* MT = maskT + (size_t)n * MASKW * MROWS;

    for (int i = lane; i < 1024; i += 64) keep_lds[i] = 0;   // single wave: no barrier

    int cnt = 0, cntprev = 0;
    u64 keptprev = 0ull;
    bool full = false;
    int nchunks = (V + 63) >> 6;

    u64 bulk[16];
#pragma unroll
    for (int q = 0; q < 16; ++q) bulk[q] = 0ull;
    u64 wc = MT[lane];      // word 0 of chunk 0 rows
    u64 nc = 0ull;

    for (int c = 0; c < nchunks && !full; ++c) {
        // ---- assemble suppression word c from pipelined inputs ----
        u64 part = 0ull;
#pragma unroll
        for (int q = 0; q < 16; ++q)
            part |= (q * 64 + lane < cntprev) ? bulk[q] : 0ull;
        part |= ((keptprev >> lane) & 1ull) ? nc : 0ull;

        unsigned plo = or_red_dpp((unsigned)part);
        unsigned phi = or_red_dpp((unsigned)(part >> 32));
        u64 cur = ((u64)(unsigned)__builtin_amdgcn_readlane((int)phi, 63) << 32)
                | (u64)(unsigned)__builtin_amdgcn_readlane((int)plo, 63);

        // ---- issue generation c+1 (all latency hidden under chain + next top) ----
        int cntNow = cnt;                       // keep list through chain c-1
        int colN = (c + 1 < NCHUNK) ? (c + 1) : (NCHUNK - 1);   // clamp: stay in-bounds
        const u64* colNp = MT + (size_t)colN * MROWS;
        {
            int kr[16];
#pragma unroll
            for (int q = 0; q < 16; ++q) kr[q] = keep_lds[q * 64 + lane];
#pragma unroll
            for (int q = 0; q < 16; ++q) bulk[q] = colNp[kr[q]];
        }
        u64 nc_next = colNp[(size_t)c * 64 + lane];          // word c+1 of chunk c rows
        u64 wc_next = colNp[(size_t)colN * 64 + lane];       // diagonal word c+1

        // ---- serial chain on chunk c ----
        int base = c * 64;
        int jmax = V - base; if (jmax > 64) jmax = 64;
        u64 avail = ~cur;
        if (jmax < 64) avail &= (1ull << jmax) - 1ull;
        while (avail) {
            int j = __builtin_ctzll(avail);
            if (lane == 0) keep_lds[cnt] = base + j;
            ++cnt;
            if (cnt == POST_K) { full = true; break; }
            u64 wcj = bcast64(wc, j);
            avail &= avail - 1;        // clear bit j
            avail &= ~wcj;             // suppress within-chunk victims
        }
        keptprev = 0ull;
        // recompute keptbits for chunk c (bits kept): avail-walk consumed them, so
        // rebuild from keep_lds tail (cnt - cntNow entries, all in [base, base+64))
        for (int i = cntNow + (int)lane; i < cnt; i += 64) {
            int r = keep_lds[i];
            keptprev |= 1ull << (r - base);
        }
        // OR keptprev across lanes (each lane saw a disjoint subset)
        {
            unsigned klo = or_red_dpp((unsigned)keptprev);
            unsigned khi = or_red_dpp((unsigned)(keptprev >> 32));
            keptprev = ((u64)(unsigned)__builtin_amdgcn_readlane((int)khi, 63) << 32)
                     | (u64)(unsigned)__builtin_amdgcn_readlane((int)klo, 63);
        }
        cntprev = cntNow;
        wc = wc_next;
        nc = nc_next;
    }

    for (int i = lane; i < cnt; i += 64) keep[n * POST_K + i] = keep_lds[i];
    if (lane == 0) nkept[n] = cnt;
}

__global__ void k_out(const float4* boxes, const int* keep, const int* nkept, float4* out) {
    int idx = blockIdx.x * blockDim.x + threadIdx.x;
    if (idx >= N_IMGS * POST_K) return;
    int n = idx / POST_K, k = idx - n * POST_K;
    float4 v = make_float4(0.f, 0.f, 0.f, 0.f);
    if (k < nkept[n]) v = boxes[(size_t)n * KSEL + keep[n * POST_K + k]];
    out[idx] = v;
}

extern "C" void kernel_launch(void* const* d_in, const int* in_sizes, int n_in,
                              void* d_out, int out_size, void* d_ws, size_t ws_size,
                              hipStream_t stream) {
    // dict order: obj0, delta0, obj1, delta1, ..., obj4, delta4, anchors
    Ptrs P;
    for (int l = 0; l < 5; ++l) {
        P.obj[l] = (const float*)d_in[2 * l];
        P.del[l] = (const float*)d_in[2 * l + 1];
    }
    P.anch = (const float*)d_in[10];

    // workspace carve
    size_t o = 0;
    auto alloc = [&](size_t bytes) {
        size_t cur = o;
        o = (o + bytes + 255) & ~(size_t)255;
        return cur;
    };
    size_t off_scores = alloc((size_t)N_IMGS * TOT * 4);
    size_t off_sel    = alloc((size_t)N_IMGS * KSEL * 8);
    size_t off_keys   = alloc((size_t)N_IMGS * KSEL * 8);
    size_t off_boxes  = alloc((size_t)N_IMGS * KSEL * 16);
    size_t off_nbox   = alloc((size_t)N_IMGS * KSEL * 16);
    size_t off_mask   = alloc((size_t)N_IMGS * MASKW * MROWS * 8);
    size_t off_vcnt   = alloc(N_IMGS * 4);
    size_t off_keep   = alloc((size_t)N_IMGS * POST_K * 4);
    size_t off_nkept  = alloc(N_IMGS * 4);

    float* out = (float*)d_out;
    if (o > ws_size) {  // workspace too small: emit zeros (visible failure, no crash)
        k_zero_out<<<(out_size + 255) / 256, 256, 0, stream>>>(out, out_size);
        return;
    }

    char* w = (char*)d_ws;
    unsigned* scores          = (unsigned*)(w + off_scores);
    uint2* sel                = (uint2*)(w + off_sel);
    unsigned long long* keys  = (unsigned long long*)(w + off_keys);
    float4* boxes             = (float4*)(w + off_boxes);
    float4* nboxes            = (float4*)(w + off_nbox);
    u64* maskT                = (u64*)(w + off_mask);
    int* vcnt                 = (int*)(w + off_vcnt);
    int* keep                 = (int*)(w + off_keep);
    int* nkept                = (int*)(w + off_nkept);

    k_init<<<1, 32, 0, stream>>>(vcnt);
    k_scores<<<(N_IMGS * TOT + 255) / 256, 256, 0, stream>>>(P, scores);
    k_select<<<N_IMGS * NLVL, 1024, 0, stream>>>(scores, sel);
    k_keys<<<(N_IMGS * KSEL + 255) / 256, 256, 0, stream>>>(P, sel, keys);
    k_sort<<<N_IMGS, 1024, 65536, stream>>>(keys);
    k_decode<<<(N_IMGS * KSEL + 255) / 256, 256, 0, stream>>>(P, keys, boxes, nboxes, vcnt);
    k_mask<<<dim3(NCHUNK, MASKW, N_IMGS), 64, 0, stream>>>(nboxes, maskT);
    k_scan<<<N_IMGS, 64, 0, stream>>>(maskT, vcnt, keep, nkept);
    k_out<<<(N_IMGS * POST_K + 255) / 256, 256, 0, stream>>>((const float4*)boxes, keep, nkept, (float4*)d_out);
}

// Round 11
// 360.767 us; speedup vs baseline: 1.8671x; 1.2809x over previous
//
#include <hip/hip_runtime.h>
#include <stdint.h>

#define N_IMGS 8
#define NLVL 5
#define TOT 392832          // total anchors across levels
#define PRE_K 1000
#define POST_K 1000
#define KSEL 5000           // 5 levels * 1000
#define MASKW 79            // ceil(5000/64)
#define MROWS 5056          // KSEL padded to 79 full 64-row chunks
#define NCHUNK 79
#define LPAD 1024           // per-level padded list length
#define MSLOTS (NLVL * LPAD)

typedef unsigned long long u64;

struct Ptrs {
    const float* obj[5];
    const float* del[5];
    const float* anch;
};

__device__ __forceinline__ unsigned flipf(float f) {
    unsigned u = __float_as_uint(f);
    return (u & 0x80000000u) ? ~u : (u | 0x80000000u);
}

__device__ __forceinline__ void lvl_info(int t, int& l, int& off, int& W, int& H) {
    if (t < 294912)      { l = 0; off = 0;      W = 384; H = 256; }
    else if (t < 368640) { l = 1; off = 294912; W = 192; H = 128; }
    else if (t < 387072) { l = 2; off = 368640; W = 96;  H = 64;  }
    else if (t < 391680) { l = 3; off = 387072; W = 48;  H = 32;  }
    else                 { l = 4; off = 391680; W = 24;  H = 16;  }
}

// Decode one proposal exactly as the reference (f32, no FMA contraction).
__device__ void decode_one(const Ptrs& P, int n, int t, float bx[4], bool& valid, int& lvl) {
#pragma clang fp contract(off)
    int l, off, W, H;
    lvl_info(t, l, off, W, H);
    lvl = l;
    int i = t - off;
    int a = i % 3;
    int p = i / 3;
    int y = p / W, x = p - y * W;
    const float* D = P.del[l];
    size_t plane = (size_t)W * H;
    size_t base = ((size_t)n * 12 + (size_t)a * 4) * plane + (size_t)y * W + x;
    float dx = D[base];
    float dy = D[base + plane];
    float dw = D[base + 2 * plane];
    float dh = D[base + 3 * plane];
    const float* an = P.anch + (size_t)t * 4;
    float a0 = an[0], a1 = an[1], a2 = an[2], a3 = an[3];
    float wa = a2 - a0, ha = a3 - a1;
    float cxa = a0 + 0.5f * wa, cya = a1 + 0.5f * ha;
    const float CLIP = 4.135166556742356f;  // log(1000/16) rounded to f32
    dw = fminf(dw, CLIP);
    dh = fminf(dh, CLIP);
    float cx = dx * wa + cxa;
    float cy = dy * ha + cya;
    float pw = expf(dw) * wa;
    float ph = expf(dh) * ha;
    float x1 = cx - 0.5f * pw, y1 = cy - 0.5f * ph;
    float x2 = cx + 0.5f * pw, y2 = cy + 0.5f * ph;
    x1 = fminf(fmaxf(x1, 0.f), 1536.f);
    x2 = fminf(fmaxf(x2, 0.f), 1536.f);
    y1 = fminf(fmaxf(y1, 0.f), 1024.f);
    y2 = fminf(fmaxf(y2, 0.f), 1024.f);
    bx[0] = x1; bx[1] = y1; bx[2] = x2; bx[3] = y2;
    valid = ((x2 - x1) >= 1e-3f) && ((y2 - y1) >= 1e-3f);
}

__global__ void k_init(int* vcnt) {
    int i = threadIdx.x;
    if (i < N_IMGS) vcnt[i] = KSEL;
}

__global__ void k_zero_out(float* out, int n) {
    int i = blockIdx.x * blockDim.x + threadIdx.x;
    if (i < n) out[i] = 0.f;
}

// Flatten objectness into (h,w,a) order per level, store order-flipped bits.
__global__ void k_scores(Ptrs P, unsigned* scores) {
    int idx = blockIdx.x * blockDim.x + threadIdx.x;
    if (idx >= N_IMGS * TOT) return;
    int n = idx / TOT, t = idx - n * TOT;
    int l, off, W, H;
    lvl_info(t, l, off, W, H);
    int i = t - off;
    int a = i % 3;
    int p = i / 3;
    int y = p / W, x = p - y * W;
    const float* O = P.obj[l];
    float v = O[(((size_t)n * 3 + a) * H + y) * (size_t)W + x];
    scores[idx] = flipf(v);
}

// Exact top-1000 per (image, level), lax.top_k tie semantics (score desc, index asc).
#define HCOPY 4100          // 4096 bins + 4 pad (bank decorrelation between copies)
#define CANDMAX 4096
__global__ __launch_bounds__(1024) void k_select(const unsigned* scores, uint2* sel) {
    int task = blockIdx.x;
    int n = task / 5, l = task % 5;
    int off, len;
    switch (l) {
        case 0: off = 0;      len = 294912; break;
        case 1: off = 294912; len = 73728;  break;
        case 2: off = 368640; len = 18432;  break;
        case 3: off = 387072; len = 4608;   break;
        default: off = 391680; len = 1152;  break;
    }
    const unsigned* S = scores + (size_t)n * TOT + off;
    const uint4* S4 = (const uint4*)S;
    int len4 = len >> 2;
    int t = threadIdx.x;

    __shared__ __align__(16) char smem[2 * HCOPY * 4];   // hist, later reused as cand
    unsigned* hist = (unsigned*)smem;
    unsigned long long* cand = (unsigned long long*)smem;
    __shared__ unsigned suf[1024];
    __shared__ unsigned sh_pivot, sh_krem;
    __shared__ int sh_ngt, sh_nc;

    // zero both hist copies
    for (int i = t; i < 2 * HCOPY; i += 1024) hist[i] = 0u;
    __syncthreads();

    // 12-bit histogram, copy = t&1
    unsigned* myh = hist + (t & 1) * HCOPY;
    for (int i = t; i < len4; i += 1024) {
        uint4 v = S4[i];
        atomicAdd(&myh[v.x >> 20], 1u);
        atomicAdd(&myh[v.y >> 20], 1u);
        atomicAdd(&myh[v.z >> 20], 1u);
        atomicAdd(&myh[v.w >> 20], 1u);
    }
    __syncthreads();
    // reduce copies
    for (int i = t; i < 4096; i += 1024) hist[i] += hist[HCOPY + i];
    __syncthreads();
    // per-group sums (4 bins/thread), inclusive suffix scan
    suf[t] = hist[4 * t] + hist[4 * t + 1] + hist[4 * t + 2] + hist[4 * t + 3];
    for (int d = 1; d < 1024; d <<= 1) {
        __syncthreads();
        unsigned v = (t + d < 1024) ? suf[t + d] : 0u;
        __syncthreads();
        suf[t] += v;
    }
    __syncthreads();
    // boundary group: suf[t] >= K, suf[t+1] < K
    unsigned above = (t == 1023) ? 0u : suf[t + 1];
    if (suf[t] >= PRE_K && above < PRE_K) {
        int b = 4 * t + 3;
        unsigned c = above;
        while (c + hist[b] < PRE_K) { c += hist[b]; --b; }
        sh_pivot = (unsigned)b;
        sh_krem = PRE_K - c;          // how many to take from pivot bin
        sh_ngt = 0; sh_nc = 0;
    }
    __syncthreads();
    unsigned pivot = sh_pivot;
    int krem = (int)sh_krem;
    __syncthreads();   // hist no longer needed; smem becomes cand

    // compact pass
    uint2* out = sel + (size_t)task * PRE_K;
    for (int i = t; i < len4; i += 1024) {
        uint4 v4 = S4[i];
        unsigned vv[4] = {v4.x, v4.y, v4.z, v4.w};
#pragma unroll
        for (int q = 0; q < 4; ++q) {
            unsigned v = vv[q];
            unsigned b = v >> 20;
            if (b > pivot) {
                int slot = atomicAdd(&sh_ngt, 1);
                out[slot] = make_uint2(v, (unsigned)(off + 4 * i + q));
            } else if (b == pivot) {
                int c = atomicAdd(&sh_nc, 1);
                if (c < CANDMAX)
                    cand[c] = ((unsigned long long)v << 32) | (unsigned)(off + 4 * i + q);
            }
        }
    }
    __syncthreads();
    int C = min(sh_nc, CANDMAX);
    int nbase = sh_ngt;               // == PRE_K - krem
    // exact rank among pivot-bin candidates (uniform j-loop -> LDS broadcast reads)
    for (int i = t; i < C; i += 1024) {
        unsigned long long a = cand[i];
        unsigned vi = (unsigned)(a >> 32), xi = (unsigned)a;
        int rank = 0;
        for (int j = 0; j < C; ++j) {
            unsigned long long bj = cand[j];
            unsigned vj = (unsigned)(bj >> 32), xj = (unsigned)bj;
            rank += (vj > vi) || (vj == vi && xj < xi);
        }
        if (rank < krem) out[nbase + rank] = make_uint2(vi, xi);
    }
}

// Build sort keys: ascending key order == (score desc, concat position asc).
// Invalid (too-small after clip) entries forced to the tail.
__global__ void k_keys(Ptrs P, const uint2* sel, unsigned long long* keys) {
    int idx = blockIdx.x * blockDim.x + threadIdx.x;
    if (idx >= N_IMGS * KSEL) return;
    int n = idx / KSEL;
    uint2 s = sel[idx];
    float bx[4]; bool valid; int l;
    decode_one(P, n, (int)s.y, bx, valid, l);
    unsigned long long key;
    if (valid) key = ((unsigned long long)(~s.x) << 32) | (unsigned long long)s.y;
    else       key = 0xFFFFFFFF00000000ull | (unsigned long long)s.y;
    keys[idx] = key;
}

// Per-(image,level) bitonic sort of 1000 keys padded to 1024, in 8 KiB LDS.
__global__ __launch_bounds__(1024) void k_sort1(const u64* keys, u64* keys2) {
    __shared__ u64 s[LPAD];
    int task = blockIdx.x;          // n*5 + l
    int n = task / 5, l = task % 5;
    int t = threadIdx.x;
    const u64* K = keys + (size_t)n * KSEL + (size_t)l * PRE_K;
    s[t] = (t < PRE_K) ? K[t] : ~0ull;
    for (int k = 2; k <= LPAD; k <<= 1) {
        for (int j = k >> 1; j > 0; j >>= 1) {
            __syncthreads();
            int ixj = t ^ j;
            if (ixj > t) {
                u64 a = s[t], b = s[ixj];
                bool asc = ((t & k) == 0);
                if (asc ? (a > b) : (a < b)) { s[t] = b; s[ixj] = a; }
            }
        }
    }
    __syncthreads();
    keys2[(size_t)task * LPAD + t] = s[t];
}

// Stable 5-way merge by rank: global rank = own position + per-other-list
// binary-search count (<= for lists with smaller index, < otherwise).
// Real keys are unique (embed anchor index) and < pad key ~0ull, so they
// occupy exactly ranks 0..4999; pads land at rank >= 5000 and are dropped.
__global__ void k_merge(const u64* keys2, u64* keys) {
    int idx = blockIdx.x * blockDim.x + threadIdx.x;
    if (idx >= N_IMGS * MSLOTS) return;
    int n = idx / MSLOTS, slot = idx - n * MSLOTS;
    int l = slot >> 10, p = slot & (LPAD - 1);
    const u64* base = keys2 + (size_t)n * MSLOTS;
    u64 key = base[(size_t)l * LPAD + p];
    int rank = p;
#pragma unroll
    for (int m = 0; m < NLVL; ++m) {
        if (m == l) continue;
        const u64* L = base + (size_t)m * LPAD;
        bool le = (m < l);   // count <= for stability when m precedes l
        int lo = 0, hi = LPAD;
        while (lo < hi) {    // 1025 possible answers -> up to 11 iterations
            int mid = (lo + hi) >> 1;
            u64 v = L[mid];
            bool take = le ? (v <= key) : (v < key);
            if (take) lo = mid + 1; else hi = mid;
        }
        rank += lo;
    }
    if (rank < KSEL) keys[(size_t)n * KSEL + rank] = key;
}

// Re-decode in sorted order; emit clipped boxes + level-offset NMS boxes; find valid count.
__global__ void k_decode(Ptrs P, const unsigned long long* keys,
                         float4* boxes, float4* nboxes, int* vcnt) {
    int idx = blockIdx.x * blockDim.x + threadIdx.x;
    if (idx >= N_IMGS * KSEL) return;
    int n = idx / KSEL, r = idx - n * KSEL;
    unsigned long long key = keys[idx];
    if ((key >> 32) == 0xFFFFFFFFull) {
        boxes[idx] = make_float4(0.f, 0.f, 0.f, 0.f);
        nboxes[idx] = make_float4(0.f, 0.f, 0.f, 0.f);
        atomicMin(&vcnt[n], r);
        return;
    }
    int t = (int)(key & 0xFFFFFFFFull);
    float bx[4]; bool valid; int l;
    decode_one(P, n, t, bx, valid, l);
    boxes[idx] = make_float4(bx[0], bx[1], bx[2], bx[3]);
    float offv = (float)l * 1537.0f;   // (max(H,W)+1) * level
    nboxes[idx] = make_float4(bx[0] + offv, bx[1] + offv, bx[2] + offv, bx[3] + offv);
}

// Suppression bitmask, TRANSPOSED layout: maskT[(n*MASKW + cword)*MROWS + r].
// Bit cc of maskT[cword][r] set iff IoU(r, cword*64+cc) > 0.7 and col > r.
// Only upper-triangular blocks (cb >= rb) written; k_scan only reads
// maskT[cword][r] for rows r kept in chunks <= cword, which are all written.
__global__ __launch_bounds__(64) void k_mask(const float4* nboxes, u64* maskT) {
#pragma clang fp contract(off)
    int rb = blockIdx.x, cb = blockIdx.y, n = blockIdx.z;
    if (cb < rb) return;
    __shared__ float4 cbox[64];
    int tid = threadIdx.x;
    int c0 = cb * 64;
    cbox[tid] = (c0 + tid < KSEL) ? nboxes[(size_t)n * KSEL + c0 + tid]
                                  : make_float4(0.f, 0.f, 0.f, 0.f);
    __syncthreads();
    int r = rb * 64 + tid;
    if (r >= KSEL) return;
    float4 rb4 = nboxes[(size_t)n * KSEL + r];
    float areaR = (rb4.z - rb4.x) * (rb4.w - rb4.y);
    u64 bits = 0ull;
    for (int cc = 0; cc < 64; ++cc) {
        int c = c0 + cc;
        if (c >= KSEL) break;
        if (c <= r) continue;
        float4 c4 = cbox[cc];
        float areaC = (c4.z - c4.x) * (c4.w - c4.y);
        float ltx = fmaxf(rb4.x, c4.x), lty = fmaxf(rb4.y, c4.y);
        float rbx = fminf(rb4.z, c4.z), rby = fminf(rb4.w, c4.w);
        float wv = fmaxf(rbx - ltx, 0.f), hv = fmaxf(rby - lty, 0.f);
        float inter = wv * hv;
        float iou = inter / (areaR + areaC - inter);   // NaN compares false, as in JAX
        if (iou > 0.7f) bits |= (1ull << cc);
    }
    maskT[((size_t)n * MASKW + cb) * MROWS + r] = bits;   // coalesced across tid
}

__device__ __forceinline__ u64 bcast64(u64 v, int src) {
    unsigned lo = (unsigned)__builtin_amdgcn_readlane((int)(unsigned)v, src);
    unsigned hi = (unsigned)__builtin_amdgcn_readlane((int)(unsigned)(v >> 32), src);
    return ((u64)hi << 32) | (u64)lo;
}

// Wave64 OR-reduce via DPP (AMD GCN canonical sequence), result in lane 63.
__device__ __forceinline__ unsigned or_red_dpp(unsigned v) {
    v |= (unsigned)__builtin_amdgcn_update_dpp(0, (int)v, 0x111, 0xf, 0xf, true);  // row_shr:1
    v |= (unsigned)__builtin_amdgcn_update_dpp(0, (int)v, 0x112, 0xf, 0xf, true);  // row_shr:2
    v |= (unsigned)__builtin_amdgcn_update_dpp(0, (int)v, 0x114, 0xf, 0xf, true);  // row_shr:4
    v |= (unsigned)__builtin_amdgcn_update_dpp(0, (int)v, 0x118, 0xf, 0xf, true);  // row_shr:8
    v |= (unsigned)__builtin_amdgcn_update_dpp(0, (int)v, 0x142, 0xa, 0xf, false); // row_bcast:15
    v |= (unsigned)__builtin_amdgcn_update_dpp(0, (int)v, 0x143, 0xc, 0xf, false); // row_bcast:31
    return v;
}

// Single-wave greedy NMS scan, fully software-pipelined: all loads for chunk c
// are issued during chunk c-1, so the per-chunk critical path is VALU/SALU only
// (DPP OR-reduce + ctz chain). Inputs per chunk c:
//   bulk[16]: word c of rows kept through chunk c-2 (unrolled register gather);
//   nc: word c of ALL rows of chunk c-1 (coalesced), masked by keptbits_{c-1};
//   wc: word c of chunk c's rows (diagonal, coalesced).
// Coverage: bulk (chunks <= c-2) + nc (chunk c-1) + in-chain wc (chunk c) = all.
// OR double-counting is harmless; keep_lds zero-init keeps idle gather slots on
// row 0 (valid, masked out by the cnt predicate).
__global__ __launch_bounds__(64, 1) void k_scan(const u64* maskT, const int* vcnt,
                                                int* keep, int* nkept) {
    __shared__ int keep_lds[1024];
    int n = blockIdx.x, lane = threadIdx.x;
    int V = vcnt[n];
    const u64* MT = maskT + (size_t)n * MASKW * MROWS;

    for (int i = lane; i < 1024; i += 64) keep_lds[i] = 0;   // single wave: no barrier

    int cnt = 0, cntprev = 0;
    u64 keptprev = 0ull;
    bool full = false;
    int nchunks = (V + 63) >> 6;

    u64 bulk[16];
#pragma unroll
    for (int q = 0; q < 16; ++q) bulk[q] = 0ull;
    u64 wc = MT[lane];      // word 0 of chunk 0 rows
    u64 nc = 0ull;

    for (int c = 0; c < nchunks && !full; ++c) {
        // ---- assemble suppression word c from pipelined inputs ----
        u64 part = 0ull;
#pragma unroll
        for (int q = 0; q < 16; ++q)
            part |= (q * 64 + lane < cntprev) ? bulk[q] : 0ull;
        part |= ((keptprev >> lane) & 1ull) ? nc : 0ull;

        unsigned plo = or_red_dpp((unsigned)part);
        unsigned phi = or_red_dpp((unsigned)(part >> 32));
        u64 cur = ((u64)(unsigned)__builtin_amdgcn_readlane((int)phi, 63) << 32)
                | (u64)(unsigned)__builtin_amdgcn_readlane((int)plo, 63);

        // ---- issue generation c+1 (all latency hidden under chain + next top) ----
        int cntNow = cnt;                       // keep list through chain c-1
        int colN = (c + 1 < NCHUNK) ? (c + 1) : (NCHUNK - 1);   // clamp: stay in-bounds
        const u64* colNp = MT + (size_t)colN * MROWS;
        {
            int kr[16];
#pragma unroll
            for (int q = 0; q < 16; ++q) kr[q] = keep_lds[q * 64 + lane];
#pragma unroll
            for (int q = 0; q < 16; ++q) bulk[q] = colNp[kr[q]];
        }
        u64 nc_next = colNp[(size_t)c * 64 + lane];          // word c+1 of chunk c rows
        u64 wc_next = colNp[(size_t)colN * 64 + lane];       // diagonal word c+1

        // ---- serial chain on chunk c ----
        int base = c * 64;
        int jmax = V - base; if (jmax > 64) jmax = 64;
        u64 avail = ~cur;
        if (jmax < 64) avail &= (1ull << jmax) - 1ull;
        while (avail) {
            int j = __builtin_ctzll(avail);
            if (lane == 0) keep_lds[cnt] = base + j;
            ++cnt;
            if (cnt == POST_K) { full = true; break; }
            u64 wcj = bcast64(wc, j);
            avail &= avail - 1;        // clear bit j
            avail &= ~wcj;             // suppress within-chunk victims
        }
        keptprev = 0ull;
        // rebuild keptbits for chunk c from keep_lds tail
        for (int i = cntNow + (int)lane; i < cnt; i += 64) {
            int r = keep_lds[i];
            keptprev |= 1ull << (r - base);
        }
        // OR keptprev across lanes (each lane saw a disjoint subset)
        {
            unsigned klo = or_red_dpp((unsigned)keptprev);
            unsigned khi = or_red_dpp((unsigned)(keptprev >> 32));
            keptprev = ((u64)(unsigned)__builtin_amdgcn_readlane((int)khi, 63) << 32)
                     | (u64)(unsigned)__builtin_amdgcn_readlane((int)klo, 63);
        }
        cntprev = cntNow;
        wc = wc_next;
        nc = nc_next;
    }

    for (int i = lane; i < cnt; i += 64) keep[n * POST_K + i] = keep_lds[i];
    if (lane == 0) nkept[n] = cnt;
}

__global__ void k_out(const float4* boxes, const int* keep, const int* nkept, float4* out) {
    int idx = blockIdx.x * blockDim.x + threadIdx.x;
    if (idx >= N_IMGS * POST_K) return;
    int n = idx / POST_K, k = idx - n * POST_K;
    float4 v = make_float4(0.f, 0.f, 0.f, 0.f);
    if (k < nkept[n]) v = boxes[(size_t)n * KSEL + keep[n * POST_K + k]];
    out[idx] = v;
}

extern "C" void kernel_launch(void* const* d_in, const int* in_sizes, int n_in,
                              void* d_out, int out_size, void* d_ws, size_t ws_size,
                              hipStream_t stream) {
    // dict order: obj0, delta0, obj1, delta1, ..., obj4, delta4, anchors
    Ptrs P;
    for (int l = 0; l < 5; ++l) {
        P.obj[l] = (const float*)d_in[2 * l];
        P.del[l] = (const float*)d_in[2 * l + 1];
    }
    P.anch = (const float*)d_in[10];

    // workspace carve
    size_t o = 0;
    auto alloc = [&](size_t bytes) {
        size_t cur = o;
        o = (o + bytes + 255) & ~(size_t)255;
        return cur;
    };
    size_t off_scores = alloc((size_t)N_IMGS * TOT * 4);
    size_t off_sel    = alloc((size_t)N_IMGS * KSEL * 8);
    size_t off_keys   = alloc((size_t)N_IMGS * KSEL * 8);
    size_t off_keys2  = alloc((size_t)N_IMGS * MSLOTS * 8);
    size_t off_boxes  = alloc((size_t)N_IMGS * KSEL * 16);
    size_t off_nbox   = alloc((size_t)N_IMGS * KSEL * 16);
    size_t off_mask   = alloc((size_t)N_IMGS * MASKW * MROWS * 8);
    size_t off_vcnt   = alloc(N_IMGS * 4);
    size_t off_keep   = alloc((size_t)N_IMGS * POST_K * 4);
    size_t off_nkept  = alloc(N_IMGS * 4);

    float* out = (float*)d_out;
    if (o > ws_size) {  // workspace too small: emit zeros (visible failure, no crash)
        k_zero_out<<<(out_size + 255) / 256, 256, 0, stream>>>(out, out_size);
        return;
    }

    char* w = (char*)d_ws;
    unsigned* scores          = (unsigned*)(w + off_scores);
    uint2* sel                = (uint2*)(w + off_sel);
    unsigned long long* keys  = (unsigned long long*)(w + off_keys);
    u64* keys2                = (u64*)(w + off_keys2);
    float4* boxes             = (float4*)(w + off_boxes);
    float4* nboxes            = (float4*)(w + off_nbox);
    u64* maskT                = (u64*)(w + off_mask);
    int* vcnt                 = (int*)(w + off_vcnt);
    int* keep                 = (int*)(w + off_keep);
    int* nkept                = (int*)(w + off_nkept);

    k_init<<<1, 32, 0, stream>>>(vcnt);
    k_scores<<<(N_IMGS * TOT + 255) / 256, 256, 0, stream>>>(P, scores);
    k_select<<<N_IMGS * NLVL, 1024, 0, stream>>>(scores, sel);
    k_keys<<<(N_IMGS * KSEL + 255) / 256, 256, 0, stream>>>(P, sel, keys);
    k_sort1<<<N_IMGS * NLVL, 1024, 0, stream>>>(keys, keys2);
    k_merge<<<(N_IMGS * MSLOTS + 255) / 256, 256, 0, stream>>>(keys2, keys);
    k_decode<<<(N_IMGS * KSEL + 255) / 256, 256, 0, stream>>>(P, keys, boxes, nboxes, vcnt);
    k_mask<<<dim3(NCHUNK, MASKW, N_IMGS), 64, 0, stream>>>(nboxes, maskT);
    k_scan<<<N_IMGS, 64, 0, stream>>>(maskT, vcnt, keep, nkept);
    k_out<<<(N_IMGS * POST_K + 255) / 256, 256, 0, stream>>>((const float4*)boxes, keep, nkept, (float4*)d_out);
}